// Round 1
// 410.452 us; speedup vs baseline: 1.0559x; 1.0559x over previous
//
#include <hip/hip_runtime.h>
#include <hip/hip_bf16.h>
#include <stdint.h>
#include <stddef.h>

// ---------------------------------------------------------------------------
// MoE MLP (no inter-GEMM nonlinearity). Inputs/outputs FP32; internal GEMMs
// bf16 MFMA. MT_e = (W1_e @ W2_e)^T precomputed once, then
// out[t] += w_k * (x[t] @ M_{e_k}) via fp32 atomics.
// R1 changes vs 433us baseline:
//   - x pre-converted to bf16 (XB, aliases dead W2T region; ws still 49MB)
//   - gemm_moe: A (gathered XB rows) and B (MT) staged via global_load_lds
//     dwordx4 (per-lane gathered global addr, linear LDS dest, XOR swizzle
//     moved to per-lane SOURCE chunk — same involution as the ds_read side)
//   - gemm_mt: A (W2T bf16) via global_load_lds; B stays fp32 reg-pack
//   - XCD-expert affinity: blockIdx.x = expert -> linear%8 = e -> MT_e /
//     W2T_e stay resident in one XCD's L2 (kills the 8x MT re-fetch)
// ---------------------------------------------------------------------------

typedef unsigned short ushort_t;                                   // bf16 bits
typedef __attribute__((ext_vector_type(8))) short short8;          // MFMA A/B frag
typedef __attribute__((ext_vector_type(4))) float floatx4;         // MFMA C/D frag

#define T_TOK 8192
#define NE    8
#define DD    1024
#define FF    2048
#define W1ROW (NE * FF)     // 16384

#define BM 128
#define BN 128
#define BK 64

typedef const __attribute__((address_space(1))) unsigned int gas_u32;
typedef __attribute__((address_space(3)))       unsigned int las_u32;
// async global->LDS, 16B/lane, LDS dest = wave-uniform base + lane*16
#define GLOAD16(gp, lp) \
  __builtin_amdgcn_global_load_lds((gas_u32*)(gp), (las_u32*)(lp), 16, 0, 0)

__device__ __forceinline__ unsigned short f2bf(float f) {
  union { float f; unsigned u; } c; c.f = f;
  unsigned r = c.u + 0x7fffu + ((c.u >> 16) & 1u);   // RNE
  return (unsigned short)(r >> 16);
}
// pack two fp32 -> two bf16 (round-half-up): 2 adds + 1 v_perm
__device__ __forceinline__ unsigned packbf2(float a, float b) {
  unsigned ua = __float_as_uint(a) + 0x8000u;
  unsigned ub = __float_as_uint(b) + 0x8000u;
  return __builtin_amdgcn_perm(ub, ua, 0x07060302);  // [ub.hi16 | ua.hi16]
}

// ---------------- workspace layout (bytes) ----------------------------------
static const size_t OFF_CNT   = 0;                       // 8 * int
static const size_t OFF_ZPART = 256;                     // 64 * float
static const size_t OFF_PPART = 512;                     // 512 * float
static const size_t OFF_REXP  = 4096;                    // 8192 * uint
static const size_t OFF_RWTS  = 36864;                   // 8192 * float2
static const size_t OFF_IDS   = 102400;                  // 8*8192 int
static const size_t OFF_WTS   = 364544;                  // 8*8192 float
static const size_t OFF_W2T   = 1048576;                 // 8*1024*2048 bf16 (32MB)
static const size_t OFF_MT    = OFF_W2T + 33554432;      // 8*1024*1024 bf16 (16MB)
// XB (8192*1024 bf16, 16MB) ALIASES OFF_W2T: W2T dead after gemm_mt,
// convert_x launches after gemm_mt (stream-ordered). total stays 51,380,224 B.
static const size_t OFF_XB    = OFF_W2T;

// ---------------- 1. router (pure fp32, matches reference logits) -----------
__global__ __launch_bounds__(256)
void router_kernel(const float* __restrict__ x, const float* __restrict__ wrt,
                   unsigned* __restrict__ rexp, float2* __restrict__ rwts,
                   float* __restrict__ zpart, float* __restrict__ ppart) {
  int w = threadIdx.x >> 6, ln = threadIdx.x & 63;
  int t = blockIdx.x * 4 + w;
  const float* xr = x + (size_t)t * DD;
  float acc[8] = {0.f, 0.f, 0.f, 0.f, 0.f, 0.f, 0.f, 0.f};
  for (int i = 0; i < 16; ++i) {
    int d = ln + (i << 6);
    float xv = xr[d];
    float4 r0 = *(const float4*)(wrt + (size_t)d * 8);
    float4 r1 = *(const float4*)(wrt + (size_t)d * 8 + 4);
    acc[0] += xv * r0.x;  acc[1] += xv * r0.y;
    acc[2] += xv * r0.z;  acc[3] += xv * r0.w;
    acc[4] += xv * r1.x;  acc[5] += xv * r1.y;
    acc[6] += xv * r1.z;  acc[7] += xv * r1.w;
  }
#pragma unroll
  for (int e = 0; e < 8; ++e) {
#pragma unroll
    for (int off = 32; off > 0; off >>= 1) acc[e] += __shfl_xor(acc[e], off, 64);
  }
  if (ln == 0) {
    float m = acc[0];
#pragma unroll
    for (int e = 1; e < 8; ++e) m = fmaxf(m, acc[e]);
    float p[8], s = 0.f;
#pragma unroll
    for (int e = 0; e < 8; ++e) { p[e] = expf(acc[e] - m); s += p[e]; }
    float z = m + logf(s);
    // top-2, ties -> lowest index (matches lax.top_k)
    int e1 = 0; float v1 = acc[0];
#pragma unroll
    for (int e = 1; e < 8; ++e) if (acc[e] > v1) { v1 = acc[e]; e1 = e; }
    int e2 = (e1 == 0) ? 1 : 0; float v2 = acc[e2];
#pragma unroll
    for (int e = 0; e < 8; ++e) if (e != e1 && acc[e] > v2) { v2 = acc[e]; e2 = e; }
    float p1 = p[e1], p2 = p[e2];
    float inv = 1.f / (p1 + p2);
    rexp[t] = (unsigned)e1 | ((unsigned)e2 << 8);
    rwts[t] = make_float2(p1 * inv, p2 * inv);
    int sh = blockIdx.x & 63;   // contention-spread partials
    unsafeAtomicAdd(&zpart[sh], z * z);
    float sinv = 1.f / s;
#pragma unroll
    for (int e = 0; e < 8; ++e) unsafeAtomicAdd(&ppart[sh * 8 + e], p[e] * sinv);
  }
}

// ---------------- 2. per-expert token lists ---------------------------------
__global__ __launch_bounds__(256)
void build_lists_kernel(const unsigned* __restrict__ rexp, const float2* __restrict__ rwts,
                        int* __restrict__ cnt, int* __restrict__ ids, float* __restrict__ wts) {
  __shared__ int lcnt[8];
  __shared__ int lbase[8];
  if (threadIdx.x < 8) lcnt[threadIdx.x] = 0;
  __syncthreads();
  int t = blockIdx.x * 256 + threadIdx.x;
  unsigned re = rexp[t];
  float2 w = rwts[t];
  int e1 = (int)(re & 0xffu), e2 = (int)((re >> 8) & 0xffu);
  int p1 = atomicAdd(&lcnt[e1], 1);
  int p2 = atomicAdd(&lcnt[e2], 1);
  __syncthreads();
  if (threadIdx.x < 8) lbase[threadIdx.x] = atomicAdd(&cnt[threadIdx.x], lcnt[threadIdx.x]);
  __syncthreads();
  int i1 = e1 * T_TOK + lbase[e1] + p1;
  ids[i1] = t;  wts[i1] = w.x;
  int i2 = e2 * T_TOK + lbase[e2] + p2;
  ids[i2] = t;  wts[i2] = w.y;
}

// ---------------- 3. W2 (fp32 [e*FF+f][j]) -> W2T (bf16 [e][j][f]) ----------
__global__ __launch_bounds__(256)
void transpose_w2_kernel(const float* __restrict__ w2, ushort_t* __restrict__ W2T) {
  __shared__ ushort_t tile[64 * 72];    // row stride 72 u16 (144B, 16B-aligned)
  int e = blockIdx.z, f0 = blockIdx.x * 64, j0 = blockIdx.y * 64;
  int tid = (int)threadIdx.x;
  int r = tid >> 2, c0 = (tid & 3) * 16;
  const float* src = w2 + ((size_t)(e * FF + f0 + r)) * DD + j0 + c0;
  float4 v0 = *(const float4*)(src);
  float4 v1 = *(const float4*)(src + 4);
  float4 v2 = *(const float4*)(src + 8);
  float4 v3 = *(const float4*)(src + 12);
  uint4 pa = make_uint4(packbf2(v0.x, v0.y), packbf2(v0.z, v0.w),
                        packbf2(v1.x, v1.y), packbf2(v1.z, v1.w));
  uint4 pb = make_uint4(packbf2(v2.x, v2.y), packbf2(v2.z, v2.w),
                        packbf2(v3.x, v3.y), packbf2(v3.z, v3.w));
  *(uint4*)&tile[r * 72 + c0]     = pa;
  *(uint4*)&tile[r * 72 + c0 + 8] = pb;
  __syncthreads();
  int j = tid >> 2, g0 = (tid & 3) * 16;
  ushort_t o[16];
#pragma unroll
  for (int i = 0; i < 16; ++i) o[i] = tile[(g0 + i) * 72 + j];
  ushort_t* dst = W2T + ((size_t)(e * DD + j0 + j)) * FF + f0 + g0;
  *(uint4*)(dst)     = *(uint4*)&o[0];
  *(uint4*)(dst + 8) = *(uint4*)&o[8];
}

// ---------------- 3b. x (fp32) -> XB (bf16), layout-preserving --------------
__global__ __launch_bounds__(256)
void convert_x_kernel(const float* __restrict__ x, ushort_t* __restrict__ XB) {
  size_t i = ((size_t)blockIdx.x * 256 + threadIdx.x) * 8;   // 8 floats/thread
  float4 f0 = *(const float4*)(x + i);
  float4 f1 = *(const float4*)(x + i + 4);
  uint4 pk = make_uint4(packbf2(f0.x, f0.y), packbf2(f0.z, f0.w),
                        packbf2(f1.x, f1.y), packbf2(f1.z, f1.w));
  *(uint4*)(XB + i) = pk;
}

// ---------------- 4. MT_e[m=j][n=i] = sum_f W2T[j][f] * W1[i][f] ------------
// grid (NE, DD/BM, DD/BN): blockIdx.x = e -> linear%8 = e -> XCD affinity
__global__ __launch_bounds__(256)
void gemm_mt_kernel(const ushort_t* __restrict__ W2T, const float* __restrict__ w1,
                    ushort_t* __restrict__ MT) {
  int e  = blockIdx.x;
  int m0 = blockIdx.y * BM;   // m = output dim j (W2 col)
  int n0 = blockIdx.z * BN;   // n = input dim i (W1 row)
  __shared__ alignas(16) ushort_t As[BM * BK];
  __shared__ alignas(16) ushort_t Bs[BN * BK];
  const ushort_t* Abase = W2T + (size_t)e * DD * FF;
  int tid = (int)threadIdx.x;
  int w = tid >> 6, ln = tid & 63;
  int wr = w >> 1, wc = w & 1;
  int mrow = ln & 15, kq = ln >> 4;
  // A gload addresses: 4 issues/wave, each 8 rows x 8 chunks of 16B.
  // source chunk = (lane&7) ^ (r&7)  -> linear LDS holds chunk c^(r&7) at c,
  // matching the ds_read side's  q ^ (r&7)  lookup (involution).
  const ushort_t* agp[4];
#pragma unroll
  for (int it = 0; it < 4; ++it) {
    int r  = w * 32 + it * 8 + (ln >> 3);
    int cs = (ln & 7) ^ (r & 7);
    agp[it] = Abase + (size_t)(m0 + r) * FF + cs * 8;
  }
  floatx4 acc[4][4] = {};
  for (int k0 = 0; k0 < FF; k0 += BK) {
    __syncthreads();
#pragma unroll
    for (int it = 0; it < 4; ++it)         // A: async global->LDS (bf16)
      GLOAD16(agp[it] + k0, &As[(w * 32 + it * 8) * BK]);
#pragma unroll
    for (int it = 0; it < 4; ++it) {       // B: W1 rows (fp32 -> pack bf16)
      int c = it * 256 + tid;
      int r = c >> 3, b = c & 7;
      const float* p = w1 + (size_t)(n0 + r) * W1ROW + e * FF + k0 + b * 8;
      float4 f0 = *(const float4*)(p);
      float4 f1 = *(const float4*)(p + 4);
      uint4 pk = make_uint4(packbf2(f0.x, f0.y), packbf2(f0.z, f0.w),
                            packbf2(f1.x, f1.y), packbf2(f1.z, f1.w));
      *(uint4*)&Bs[r * BK + ((b ^ (r & 7)) << 3)] = pk;
    }
    __syncthreads();                        // drains vmcnt+lgkmcnt
#pragma unroll
    for (int s = 0; s < 2; ++s) {
      short8 fa[4], fb[4];
#pragma unroll
      for (int i = 0; i < 4; ++i) {
        int r = wr * 64 + i * 16 + mrow;
        fa[i] = *(const short8*)&As[r * BK + ((((s << 2) | kq) ^ (r & 7)) << 3)];
      }
#pragma unroll
      for (int j = 0; j < 4; ++j) {
        int r = wc * 64 + j * 16 + mrow;
        fb[j] = *(const short8*)&Bs[r * BK + ((((s << 2) | kq) ^ (r & 7)) << 3)];
      }
#pragma unroll
      for (int i = 0; i < 4; ++i)
#pragma unroll
        for (int j = 0; j < 4; ++j)
          acc[i][j] = __builtin_amdgcn_mfma_f32_16x16x32_bf16(fa[i], fb[j], acc[i][j], 0, 0, 0);
    }
  }
  // epilogue: C/D layout col=lane&15, row=(lane>>4)*4+reg
  ushort_t* outp = MT + (size_t)e * DD * DD;
#pragma unroll
  for (int i = 0; i < 4; ++i) {
#pragma unroll
    for (int j = 0; j < 4; ++j) {
#pragma unroll
      for (int rr = 0; rr < 4; ++rr) {
        int m = m0 + wr * 64 + i * 16 + kq * 4 + rr;
        int n = n0 + wc * 64 + j * 16 + mrow;
        outp[(size_t)m * DD + n] = f2bf(acc[i][j][rr]);
      }
    }
  }
}

// ---------------- 5. gathered token GEMM: out[t] += w * (x[t] @ M_e) --------
// grid (NE, T_TOK/BM, DD/BN): blockIdx.x = e -> XCD affinity: MT_e (2MB)
// stays resident in XCD-e's 4MB L2.
__global__ __launch_bounds__(256)
void gemm_moe_kernel(const ushort_t* __restrict__ XB, const ushort_t* __restrict__ MT,
                     const int* __restrict__ cnt, const int* __restrict__ ids,
                     const float* __restrict__ wts, float* __restrict__ outp) {
  int e = blockIdx.x;
  int ce = cnt[e];
  int s0 = blockIdx.y * BM;
  if (s0 >= ce) return;                 // block-uniform early exit
  int n0 = blockIdx.z * BN;
  __shared__ int   rid_l[BM];
  __shared__ float wrow[BM];
  __shared__ alignas(16) ushort_t As[BM * BK];
  __shared__ alignas(16) ushort_t Bs[BN * BK];
  int tid = (int)threadIdx.x;
  if (tid < BM) {
    int s = s0 + tid;
    if (s < ce) { rid_l[tid] = ids[e * T_TOK + s]; wrow[tid] = wts[e * T_TOK + s]; }
    else        { rid_l[tid] = 0;                  wrow[tid] = 0.f; }
  }
  __syncthreads();
  const ushort_t* Bbase = MT + (size_t)e * DD * DD;
  int w = tid >> 6, ln = tid & 63;
  int wr = w >> 1, wc = w & 1;
  int mrow = ln & 15, kq = ln >> 4;
  // per-lane gathered A addresses (token row in XB) + B addresses (MT rows),
  // source-chunk XOR swizzle, fixed across the K loop.
  const ushort_t* agp[4];
  const ushort_t* bgp[4];
#pragma unroll
  for (int it = 0; it < 4; ++it) {
    int r  = w * 32 + it * 8 + (ln >> 3);
    int cs = (ln & 7) ^ (r & 7);
    int tok = rid_l[r];
    agp[it] = XB + (size_t)tok * DD + cs * 8;
    bgp[it] = Bbase + (size_t)(n0 + r) * DD + cs * 8;
  }
  floatx4 acc[4][4] = {};
  for (int k0 = 0; k0 < DD; k0 += BK) {
    __syncthreads();
#pragma unroll
    for (int it = 0; it < 4; ++it)         // A: gathered token rows (bf16)
      GLOAD16(agp[it] + k0, &As[(w * 32 + it * 8) * BK]);
#pragma unroll
    for (int it = 0; it < 4; ++it)         // B: MT_e rows (bf16)
      GLOAD16(bgp[it] + k0, &Bs[(w * 32 + it * 8) * BK]);
    __syncthreads();                        // drains vmcnt -> LDS ready
#pragma unroll
    for (int s = 0; s < 2; ++s) {
      short8 fa[4], fb[4];
#pragma unroll
      for (int i = 0; i < 4; ++i) {
        int r = wr * 64 + i * 16 + mrow;
        fa[i] = *(const short8*)&As[r * BK + ((((s << 2) | kq) ^ (r & 7)) << 3)];
      }
#pragma unroll
      for (int j = 0; j < 4; ++j) {
        int r = wc * 64 + j * 16 + mrow;
        fb[j] = *(const short8*)&Bs[r * BK + ((((s << 2) | kq) ^ (r & 7)) << 3)];
      }
#pragma unroll
      for (int i = 0; i < 4; ++i)
#pragma unroll
        for (int j = 0; j < 4; ++j)
          acc[i][j] = __builtin_amdgcn_mfma_f32_16x16x32_bf16(fa[i], fb[j], acc[i][j], 0, 0, 0);
    }
  }
  // epilogue: fp32 atomic add into out (exactly 2 contributions per element)
#pragma unroll
  for (int i = 0; i < 4; ++i) {
#pragma unroll
    for (int j = 0; j < 4; ++j) {
#pragma unroll
      for (int rr = 0; rr < 4; ++rr) {
        int mloc = wr * 64 + i * 16 + kq * 4 + rr;
        if (s0 + mloc < ce) {
          int tok = rid_l[mloc];
          int ncol = n0 + wc * 64 + j * 16 + mrow;
          unsafeAtomicAdd(&outp[(size_t)tok * DD + ncol], acc[i][j][rr] * wrow[mloc]);
        }
      }
    }
  }
}

// ---------------- 6. losses + f_i (fp32 outputs) ----------------------------
__global__ void losses_kernel(const float* __restrict__ zpart, const float* __restrict__ ppart,
                              const int* __restrict__ cnt, float* __restrict__ outaux) {
  if (threadIdx.x == 0) {
    float z = 0.f;
    for (int i = 0; i < 64; ++i) z += zpart[i];
    z /= (float)T_TOK;
    float p[8];
    for (int e = 0; e < 8; ++e) {
      float s = 0.f;
      for (int b = 0; b < 64; ++b) s += ppart[b * 8 + e];
      p[e] = s / (float)T_TOK;
    }
    float lb = 0.f;
    for (int e = 0; e < 8; ++e) lb += ((float)cnt[e] / (float)(T_TOK * 2)) * p[e];
    lb *= (float)NE;
    outaux[0] = z;
    outaux[1] = lb;
    for (int e = 0; e < 8; ++e) outaux[2 + e] = (float)cnt[e] / (float)(T_TOK * 2);
  }
}

// ---------------- launch -----------------------------------------------------
extern "C" void kernel_launch(void* const* d_in, const int* in_sizes, int n_in,
                              void* d_out, int out_size, void* d_ws, size_t ws_size,
                              hipStream_t stream) {
  const float* x   = (const float*)d_in[0];   // [8192,1024] fp32
  const float* wrt = (const float*)d_in[1];   // [1024,8]    fp32
  const float* w1  = (const float*)d_in[2];   // [1024,16384] fp32
  const float* w2  = (const float*)d_in[3];   // [16384,1024] fp32
  float* out = (float*)d_out;                 // 8192*1024 + 1 + 1 + 8 fp32

  char* ws = (char*)d_ws;
  int*      cnt   = (int*)     (ws + OFF_CNT);
  float*    zpart = (float*)   (ws + OFF_ZPART);
  float*    ppart = (float*)   (ws + OFF_PPART);
  unsigned* rexp  = (unsigned*)(ws + OFF_REXP);
  float2*   rwts  = (float2*)  (ws + OFF_RWTS);
  int*      ids   = (int*)     (ws + OFF_IDS);
  float*    wtsf  = (float*)   (ws + OFF_WTS);
  ushort_t* W2T   = (ushort_t*)(ws + OFF_W2T);
  ushort_t* MT    = (ushort_t*)(ws + OFF_MT);
  ushort_t* XB    = (ushort_t*)(ws + OFF_XB);  // aliases W2T (dead after gemm_mt)

  hipMemsetAsync(d_ws, 0, 4096, stream);                       // cnt+zpart+ppart
  hipMemsetAsync(d_out, 0, (size_t)out_size * 4, stream);      // atomic targets
  router_kernel<<<T_TOK / 4, 256, 0, stream>>>(x, wrt, rexp, rwts, zpart, ppart);
  build_lists_kernel<<<T_TOK / 256, 256, 0, stream>>>(rexp, rwts, cnt, ids, wtsf);
  transpose_w2_kernel<<<dim3(FF / 64, DD / 64, NE), 256, 0, stream>>>(w2, W2T);
  gemm_mt_kernel<<<dim3(NE, DD / BM, DD / BN), 256, 0, stream>>>(W2T, w1, MT);
  convert_x_kernel<<<(T_TOK * DD) / (8 * 256), 256, 0, stream>>>(x, XB);   // after gemm_mt (XB aliases W2T)
  gemm_moe_kernel<<<dim3(NE, T_TOK / BM, DD / BN), 256, 0, stream>>>(XB, MT, cnt, ids, wtsf, out);
  losses_kernel<<<1, 64, 0, stream>>>(zpart, ppart, cnt, out + (size_t)T_TOK * DD);
}